// Round 8
// baseline (231.022 us; speedup 1.0000x reference)
//
#include <hip/hip_runtime.h>

// R8 = DIAGNOSTIC round: unchanged R7 kernel (passes, 135.8us incl. fa_pack)
// + fa_probe: pure-read probe of the exact feature access pattern (16B head
// of every 64B row; 64 consecutive rows per wave-instruction; 16 independent
// loads/thread; full occupancy). Probe writes only to d_ws -> output still
// produced solely by fa_mfma. dur_us(R8) - 135.8 isolates the probe's time,
// telling us whether 136us is the pattern's memory floor or an overlap limit.

typedef __attribute__((ext_vector_type(8))) short short8v;
typedef __attribute__((ext_vector_type(4))) float f32x4;

#define BN_EPS 1e-5f

__device__ __forceinline__ unsigned short f2bf(float f) {
    union { float f; unsigned u; } U; U.f = f;
    unsigned r = U.u + 0x7FFFu + ((U.u >> 16) & 1u);   // RNE; inputs finite
    return (unsigned short)(r >> 16);
}

union FragU { uint4 u; short8v s; uint2 h[2]; };

// ---- d_ws layout (bytes) ----
//     0 : W1 frags uint4[1536]  (frag = ct*3+ks, ct 0..7, ks 0..2; zero-pad k>=68)
// 24576 : W2 frags uint4[1024]  (frag = ct*4+ks, ct 0..3, ks 0..3)
// 40960 : W3 frags uint4[512]   (frag = ct*2+ks, ct 0..3, ks 0..1)
// 49152 : s1[128]  49664 : t1[128]
// 50176 : s2[64]   50432 : t2[64]
// 50688 : s3[64]   50944 : t3[64]
// 65536.. : probe scratch (2 MB)

__global__ __launch_bounds__(256) void fa_pack(
    const float* __restrict__ W1, const float* __restrict__ g1, const float* __restrict__ b1,
    const float* __restrict__ m1, const float* __restrict__ v1,
    const float* __restrict__ W2, const float* __restrict__ g2, const float* __restrict__ b2,
    const float* __restrict__ m2, const float* __restrict__ v2,
    const float* __restrict__ W3, const float* __restrict__ g3, const float* __restrict__ b3,
    const float* __restrict__ m3, const float* __restrict__ v3,
    char* __restrict__ ws)
{
    const int id = blockIdx.x * 256 + threadIdx.x;
    if (id < 1536) {                       // W1: 96(K,zero-padded) x 128
        const int lane = id & 63, frag = id >> 6;
        const int ct = frag / 3, ks = frag - 3 * ct;
        const int o  = ct * 16 + (lane & 15);
        const int kb = ks * 32 + (lane >> 4) * 8;
        unsigned short h[8];
        #pragma unroll
        for (int j = 0; j < 8; ++j) {
            const int k = kb + j;
            h[j] = (k < 68) ? f2bf(W1[o * 68 + k]) : (unsigned short)0;
        }
        uint4 pk;
        pk.x = h[0] | (h[1] << 16); pk.y = h[2] | (h[3] << 16);
        pk.z = h[4] | (h[5] << 16); pk.w = h[6] | (h[7] << 16);
        ((uint4*)ws)[id] = pk;
    } else if (id < 2560) {                // W2: 128 x 64
        const int i2 = id - 1536;
        const int lane = i2 & 63, frag = i2 >> 6;
        const int o  = (frag >> 2) * 16 + (lane & 15);
        const int kb = (frag & 3) * 32 + (lane >> 4) * 8;
        unsigned short h[8];
        #pragma unroll
        for (int j = 0; j < 8; ++j) h[j] = f2bf(W2[o * 128 + kb + j]);
        uint4 pk;
        pk.x = h[0] | (h[1] << 16); pk.y = h[2] | (h[3] << 16);
        pk.z = h[4] | (h[5] << 16); pk.w = h[6] | (h[7] << 16);
        ((uint4*)(ws + 24576))[i2] = pk;
    } else if (id < 3072) {                // W3: 64 x 64
        const int i3 = id - 2560;
        const int lane = i3 & 63, frag = i3 >> 6;
        const int o  = (frag >> 1) * 16 + (lane & 15);
        const int kb = (frag & 1) * 32 + (lane >> 4) * 8;
        unsigned short h[8];
        #pragma unroll
        for (int j = 0; j < 8; ++j) h[j] = f2bf(W3[o * 64 + kb + j]);
        uint4 pk;
        pk.x = h[0] | (h[1] << 16); pk.y = h[2] | (h[3] << 16);
        pk.z = h[4] | (h[5] << 16); pk.w = h[6] | (h[7] << 16);
        ((uint4*)(ws + 40960))[i3] = pk;
    } else if (id < 3200) {                // BN fold L1
        const int o = id - 3072;
        const float s = g1[o] * rsqrtf(v1[o] + BN_EPS);
        ((float*)(ws + 49152))[o] = s;
        ((float*)(ws + 49664))[o] = b1[o] - m1[o] * s;
    } else if (id < 3264) {                // BN fold L2
        const int o = id - 3200;
        const float s = g2[o] * rsqrtf(v2[o] + BN_EPS);
        ((float*)(ws + 50176))[o] = s;
        ((float*)(ws + 50432))[o] = b2[o] - m2[o] * s;
    } else if (id < 3328) {                // BN fold L3
        const int o = id - 3264;
        const float s = g3[o] * rsqrtf(v3[o] + BN_EPS);
        ((float*)(ws + 50688))[o] = s;
        ((float*)(ws + 50944))[o] = b3[o] - m3[o] * s;
    }
}

// Pure-read probe of the exact feature pattern: float4 at the head of each
// 64B row; wave reads 64 consecutive rows per instruction; 16 independent
// loads per thread (deep MLP); tiny kernel -> full occupancy.
__global__ __launch_bounds__(256) void fa_probe(
    const float* __restrict__ feat, float* __restrict__ wsout)
{
    const int g  = blockIdx.x * 256 + threadIdx.x;
    const int wv = g >> 6, l = g & 63;
    const size_t r0 = (size_t)wv * 1024 + l;   // 8192 waves x 1024 rows = 8.4M rows
    float ax = 0.f, ay = 0.f, az = 0.f, aw = 0.f;
    #pragma unroll
    for (int i = 0; i < 16; ++i) {
        const float4 f = *(const float4*)(feat + (r0 + (size_t)i * 64) * 16);
        ax += f.x; ay += f.y; az += f.z; aw += f.w;
    }
    wsout[g] = ax + ay + az + aw;
}

__global__ __launch_bounds__(256, 3) void fa_mfma(
    const float* __restrict__ src, const float* __restrict__ tgt,
    const float* __restrict__ feat,
    const char* __restrict__ ws, float* __restrict__ out)
{
    constexpr int N = 16384;
    __shared__ unsigned short SM[192 * 136];   // 52224 B -> 3 blocks/CU
    #define X0V(r, c) SM[(r) * 72 + (c)]
    #define X1V(r, c) SM[(r) * 136 + (c)]

    const int t  = threadIdx.x;
    const int b  = blockIdx.x >> 8;             // 8 batches x 256 tiles
    const int n0 = (blockIdx.x & 255) << 6;     // 64 points per tile

    // ---- stage X0: contiguous wave reads (64 consecutive points, 1 channel) ----
    {
        const int p  = t & 63;
        const int cg = t >> 6;                  // 0..3 (16 channels each)
        float4 fr[16];
        #pragma unroll
        for (int i = 0; i < 16; ++i) {
            const int c = cg * 16 + i;
            fr[i] = *(const float4*)(feat + ((size_t)(b * 64 + c) * N + n0 + p) * 16);
        }
        float rs0 = 0, rs1 = 0, rs2 = 0, rt0 = 0, rt1 = 0, rt2 = 0;
        const bool rel = t < 192;
        const int rp = t & 63, rk = t >> 6;     // rk 0..2 when rel
        if (rel) {
            const int n = n0 + rp;
            rs0 = src[((b * 3 + 0) * N + n) * 16 + rk]; rt0 = tgt[(b * 3 + 0) * N + n];
            rs1 = src[((b * 3 + 1) * N + n) * 16 + rk]; rt1 = tgt[(b * 3 + 1) * N + n];
            rs2 = src[((b * 3 + 2) * N + n) * 16 + rk]; rt2 = tgt[(b * 3 + 2) * N + n];
        }
        #pragma unroll
        for (int j = 0; j < 4; ++j) {
            const int c0 = cg * 16 + 4 * j;
            const float4 f0 = fr[4 * j + 0], f1 = fr[4 * j + 1];
            const float4 f2 = fr[4 * j + 2], f3 = fr[4 * j + 3];
            uint2 u0, u1, u2;
            u0.x = f2bf(f0.x) | (f2bf(f1.x) << 16); u0.y = f2bf(f2.x) | (f2bf(f3.x) << 16);
            u1.x = f2bf(f0.y) | (f2bf(f1.y) << 16); u1.y = f2bf(f2.y) | (f2bf(f3.y) << 16);
            u2.x = f2bf(f0.z) | (f2bf(f1.z) << 16); u2.y = f2bf(f2.z) | (f2bf(f3.z) << 16);
            *(uint2*)&X0V(0 * 64 + p, c0) = u0;
            *(uint2*)&X0V(1 * 64 + p, c0) = u1;
            *(uint2*)&X0V(2 * 64 + p, c0) = u2;
        }
        if (rel) {
            const float d0 = rs0 - rt0, d1 = rs1 - rt1, d2 = rs2 - rt2;
            const float ds = d0 * d0 + d1 * d1 + d2 * d2;
            uint2 wr; wr.x = f2bf(d0) | (f2bf(d1) << 16); wr.y = f2bf(d2) | (f2bf(ds) << 16);
            *(uint2*)&X0V(rk * 64 + rp, 64) = wr;
        }
    }
    __syncthreads();   // B1: X0 staged

    const int w = t >> 6, lane = t & 63, lo = lane & 15, hi = lane >> 4;

    const uint4*  w1f = (const uint4*)ws;
    const uint4*  w2f = (const uint4*)(ws + 24576);
    const uint4*  w3f = (const uint4*)(ws + 40960);
    const float*  s1w = (const float*)(ws + 49152);
    const float*  t1w = (const float*)(ws + 49664);
    const float*  s2w = (const float*)(ws + 50176);
    const float*  t2w = (const float*)(ws + 50432);
    const float*  s3w = (const float*)(ws + 50688);
    const float*  t3w = (const float*)(ws + 50944);

    // ---- layer 1 A-fragments: consume ALL of X0 into registers ----
    short8v a1[3][3];
    #pragma unroll
    for (int k = 0; k < 3; ++k) {
        const int row = k * 64 + w * 16 + lo;
        a1[k][0] = *(const short8v*)&X0V(row, hi * 8);
        a1[k][1] = *(const short8v*)&X0V(row, 32 + hi * 8);
        FragU U; U.u.x = 0; U.u.y = 0; U.u.z = 0; U.u.w = 0;
        if (hi == 0) U.h[0] = *(const uint2*)&X0V(row, 64);
        a1[k][2] = U.s;
    }
    __syncthreads();   // B2: X0 dead, X1 region free

    // ---- layer 1 : K=96 (68 real) -> 128, write X1 ----
    #pragma unroll 2
    for (int ct = 0; ct < 8; ++ct) {
        FragU B0, B1, B2;
        B0.u = w1f[(ct * 3 + 0) * 64 + lane];
        B1.u = w1f[(ct * 3 + 1) * 64 + lane];
        B2.u = w1f[(ct * 3 + 2) * 64 + lane];
        const float sc = s1w[ct * 16 + lo];
        const float tb = t1w[ct * 16 + lo];
        #pragma unroll
        for (int k = 0; k < 3; ++k) {
            f32x4 acc = {0.f, 0.f, 0.f, 0.f};
            acc = __builtin_amdgcn_mfma_f32_16x16x32_bf16(a1[k][0], B0.s, acc, 0, 0, 0);
            acc = __builtin_amdgcn_mfma_f32_16x16x32_bf16(a1[k][1], B1.s, acc, 0, 0, 0);
            acc = __builtin_amdgcn_mfma_f32_16x16x32_bf16(a1[k][2], B2.s, acc, 0, 0, 0);
            const int rb = k * 64 + w * 16 + 4 * hi;
            #pragma unroll
            for (int j = 0; j < 4; ++j) {
                const float y = fmaxf(fmaf(sc, acc[j], tb), 0.f);
                X1V(rb + j, ct * 16 + lo) = f2bf(y);
            }
        }
    }

    // ---- layer 2 A-fragments: consume X1 (wave-private rows) ----
    short8v a2[3][4];
    #pragma unroll
    for (int k = 0; k < 3; ++k) {
        const int row = k * 64 + w * 16 + lo;
        #pragma unroll
        for (int ks = 0; ks < 4; ++ks)
            a2[k][ks] = *(const short8v*)&X1V(row, ks * 32 + hi * 8);
    }
    __syncthreads();   // B3: X1 dead

    // ---- layer 2 : K=128 -> 64, write X2 (X0 view) ----
    #pragma unroll 2
    for (int ct = 0; ct < 4; ++ct) {
        FragU B0, B1, B2, B3;
        B0.u = w2f[(ct * 4 + 0) * 64 + lane];
        B1.u = w2f[(ct * 4 + 1) * 64 + lane];
        B2.u = w2f[(ct * 4 + 2) * 64 + lane];
        B3.u = w2f[(ct * 4 + 3) * 64 + lane];
        const float sc = s2w[ct * 16 + lo];
        const float tb = t2w[ct * 16 + lo];
        #pragma unroll
        for (int k = 0; k < 3; ++k) {
            f32x4 acc = {0.f, 0.f, 0.f, 0.f};
            acc = __builtin_amdgcn_mfma_f32_16x16x32_bf16(a2[k][0], B0.s, acc, 0, 0, 0);
            acc = __builtin_amdgcn_mfma_f32_16x16x32_bf16(a2[k][1], B1.s, acc, 0, 0, 0);
            acc = __builtin_amdgcn_mfma_f32_16x16x32_bf16(a2[k][2], B2.s, acc, 0, 0, 0);
            acc = __builtin_amdgcn_mfma_f32_16x16x32_bf16(a2[k][3], B3.s, acc, 0, 0, 0);
            const int rb = k * 64 + w * 16 + 4 * hi;
            #pragma unroll
            for (int j = 0; j < 4; ++j) {
                const float y = fmaxf(fmaf(sc, acc[j], tb), 0.f);
                X0V(rb + j, ct * 16 + lo) = f2bf(y);
            }
        }
    }

    // ---- layer 3 : K=64 -> 64, BN+ReLU per k then register k-sum ----
    short8v a3[3][2];
    #pragma unroll
    for (int k = 0; k < 3; ++k) {
        const int row = k * 64 + w * 16 + lo;
        a3[k][0] = *(const short8v*)&X0V(row, hi * 8);
        a3[k][1] = *(const short8v*)&X0V(row, 32 + hi * 8);
    }
    #pragma unroll 2
    for (int ct = 0; ct < 4; ++ct) {
        FragU B0, B1;
        B0.u = w3f[(ct * 2 + 0) * 64 + lane];
        B1.u = w3f[(ct * 2 + 1) * 64 + lane];
        const float sc = s3w[ct * 16 + lo];
        const float tb = t3w[ct * 16 + lo];
        f32x4 acc0 = {0.f, 0.f, 0.f, 0.f};
        f32x4 acc1 = {0.f, 0.f, 0.f, 0.f};
        f32x4 acc2 = {0.f, 0.f, 0.f, 0.f};
        acc0 = __builtin_amdgcn_mfma_f32_16x16x32_bf16(a3[0][0], B0.s, acc0, 0, 0, 0);
        acc0 = __builtin_amdgcn_mfma_f32_16x16x32_bf16(a3[0][1], B1.s, acc0, 0, 0, 0);
        acc1 = __builtin_amdgcn_mfma_f32_16x16x32_bf16(a3[1][0], B0.s, acc1, 0, 0, 0);
        acc1 = __builtin_amdgcn_mfma_f32_16x16x32_bf16(a3[1][1], B1.s, acc1, 0, 0, 0);
        acc2 = __builtin_amdgcn_mfma_f32_16x16x32_bf16(a3[2][0], B0.s, acc2, 0, 0, 0);
        acc2 = __builtin_amdgcn_mfma_f32_16x16x32_bf16(a3[2][1], B1.s, acc2, 0, 0, 0);
        float4 r;
        float* rp4 = &r.x;
        #pragma unroll
        for (int j = 0; j < 4; ++j) {
            rp4[j] = fmaxf(fmaf(sc, acc0[j], tb), 0.f)
                   + fmaxf(fmaf(sc, acc1[j], tb), 0.f)
                   + fmaxf(fmaf(sc, acc2[j], tb), 0.f);
        }
        float* op = out + (size_t)(b * 64 + ct * 16 + lo) * N + n0 + w * 16 + 4 * hi;
        *(float4*)op = r;   // 4 lanes per o cover a full 64B line
    }
    #undef X0V
    #undef X1V
}

extern "C" void kernel_launch(void* const* d_in, const int* in_sizes, int n_in,
                              void* d_out, int out_size, void* d_ws, size_t ws_size,
                              hipStream_t stream)
{
    const float* src  = (const float*)d_in[0];
    const float* tgt  = (const float*)d_in[1];
    const float* feat = (const float*)d_in[2];
    const float* W1 = (const float*)d_in[3];
    const float* g1 = (const float*)d_in[4];
    const float* b1 = (const float*)d_in[5];
    const float* m1 = (const float*)d_in[6];
    const float* v1 = (const float*)d_in[7];
    const float* W2 = (const float*)d_in[8];
    const float* g2 = (const float*)d_in[9];
    const float* b2 = (const float*)d_in[10];
    const float* m2 = (const float*)d_in[11];
    const float* v2 = (const float*)d_in[12];
    const float* W3 = (const float*)d_in[13];
    const float* g3 = (const float*)d_in[14];
    const float* b3 = (const float*)d_in[15];
    const float* m3 = (const float*)d_in[16];
    const float* v3 = (const float*)d_in[17];
    float* out = (float*)d_out;
    char* ws = (char*)d_ws;

    hipLaunchKernelGGL(fa_pack, dim3(13), dim3(256), 0, stream,
                       W1, g1, b1, m1, v1, W2, g2, b2, m2, v2, W3, g3, b3, m3, v3, ws);
    hipLaunchKernelGGL(fa_mfma, dim3(8 * 256), dim3(256), 0, stream,
                       src, tgt, feat, ws, out);
    // diagnostic probe (writes only to ws scratch, after the real kernel)
    hipLaunchKernelGGL(fa_probe, dim3(2048), dim3(256), 0, stream,
                       feat, (float*)(ws + 65536));
}

// Round 10
// 199.612 us; speedup vs baseline: 1.1574x; 1.1574x over previous
//
#include <hip/hip_runtime.h>

// FeatureAggregation via MFMA bf16 (fp32 accumulate).
// R4/R7 verified 32-pt compute core + ASYNC staging via global_load_lds
// size=4 (the HW-verified width; R9's size=12 scrambled lane strides).
// Planar LDS strip: per instruction, 64 lanes write 256B linear
// (lanes 0-31 = even channel's 32 points, 32-63 = odd channel's), matching
// the builtin's base+lane*4 dest exactly. 4 tiles/block; tile t+1's 48 loads
// are issued after B3 and drain at the top-of-loop vmcnt(0)+barrier.
// B=8, C=64, N=16384, K=16, only k<3 used (reference quirk).

typedef __attribute__((ext_vector_type(8))) short short8v;
typedef __attribute__((ext_vector_type(4))) float f32x4;

#define BN_EPS 1e-5f

__device__ __forceinline__ unsigned short f2bf(float f) {
    union { float f; unsigned u; } U; U.f = f;
    unsigned r = U.u + 0x7FFFu + ((U.u >> 16) & 1u);   // RNE; inputs finite
    return (unsigned short)(r >> 16);
}

union FragU { uint4 u; short8v s; uint2 h[2]; };

// ---- d_ws layout (bytes) ----
//     0 : W1 frags uint4[1536]  (frag = ct*3+ks; zero-pad k>=68)
// 24576 : W2 frags uint4[1024]  (frag = ct*4+ks)
// 40960 : W3 frags uint4[512]   (frag = ct*2+ks)
// 49152 : s1[128]  49664 : t1[128]
// 50176 : s2[64]   50432 : t2[64]
// 50688 : s3[64]   50944 : t3[64]

__global__ __launch_bounds__(256) void fa_pack(
    const float* __restrict__ W1, const float* __restrict__ g1, const float* __restrict__ b1,
    const float* __restrict__ m1, const float* __restrict__ v1,
    const float* __restrict__ W2, const float* __restrict__ g2, const float* __restrict__ b2,
    const float* __restrict__ m2, const float* __restrict__ v2,
    const float* __restrict__ W3, const float* __restrict__ g3, const float* __restrict__ b3,
    const float* __restrict__ m3, const float* __restrict__ v3,
    char* __restrict__ ws)
{
    const int id = blockIdx.x * 256 + threadIdx.x;
    if (id < 1536) {                       // W1: 96(K,zero-padded) x 128
        const int lane = id & 63, frag = id >> 6;
        const int ct = frag / 3, ks = frag - 3 * ct;
        const int o  = ct * 16 + (lane & 15);
        const int kb = ks * 32 + (lane >> 4) * 8;
        unsigned short h[8];
        #pragma unroll
        for (int j = 0; j < 8; ++j) {
            const int k = kb + j;
            h[j] = (k < 68) ? f2bf(W1[o * 68 + k]) : (unsigned short)0;
        }
        uint4 pk;
        pk.x = h[0] | (h[1] << 16); pk.y = h[2] | (h[3] << 16);
        pk.z = h[4] | (h[5] << 16); pk.w = h[6] | (h[7] << 16);
        ((uint4*)ws)[id] = pk;
    } else if (id < 2560) {                // W2: 128 x 64
        const int i2 = id - 1536;
        const int lane = i2 & 63, frag = i2 >> 6;
        const int o  = (frag >> 2) * 16 + (lane & 15);
        const int kb = (frag & 3) * 32 + (lane >> 4) * 8;
        unsigned short h[8];
        #pragma unroll
        for (int j = 0; j < 8; ++j) h[j] = f2bf(W2[o * 128 + kb + j]);
        uint4 pk;
        pk.x = h[0] | (h[1] << 16); pk.y = h[2] | (h[3] << 16);
        pk.z = h[4] | (h[5] << 16); pk.w = h[6] | (h[7] << 16);
        ((uint4*)(ws + 24576))[i2] = pk;
    } else if (id < 3072) {                // W3: 64 x 64
        const int i3 = id - 2560;
        const int lane = i3 & 63, frag = i3 >> 6;
        const int o  = (frag >> 1) * 16 + (lane & 15);
        const int kb = (frag & 1) * 32 + (lane >> 4) * 8;
        unsigned short h[8];
        #pragma unroll
        for (int j = 0; j < 8; ++j) h[j] = f2bf(W3[o * 64 + kb + j]);
        uint4 pk;
        pk.x = h[0] | (h[1] << 16); pk.y = h[2] | (h[3] << 16);
        pk.z = h[4] | (h[5] << 16); pk.w = h[6] | (h[7] << 16);
        ((uint4*)(ws + 40960))[i3] = pk;
    } else if (id < 3200) {                // BN fold L1
        const int o = id - 3072;
        const float s = g1[o] * rsqrtf(v1[o] + BN_EPS);
        ((float*)(ws + 49152))[o] = s;
        ((float*)(ws + 49664))[o] = b1[o] - m1[o] * s;
    } else if (id < 3264) {                // BN fold L2
        const int o = id - 3200;
        const float s = g2[o] * rsqrtf(v2[o] + BN_EPS);
        ((float*)(ws + 50176))[o] = s;
        ((float*)(ws + 50432))[o] = b2[o] - m2[o] * s;
    } else if (id < 3328) {                // BN fold L3
        const int o = id - 3264;
        const float s = g3[o] * rsqrtf(v3[o] + BN_EPS);
        ((float*)(ws + 50688))[o] = s;
        ((float*)(ws + 50944))[o] = b3[o] - m3[o] * s;
    }
}

__global__ __launch_bounds__(128, 2) void fa_mfma(
    const float* __restrict__ src, const float* __restrict__ tgt,
    const float* __restrict__ feat,
    const char* __restrict__ ws, float* __restrict__ out)
{
    constexpr int N = 16384;
    // SM: X0 view (96 x stride 72, input / layer-2 output) overlaid with
    //     X1 view (96 x stride 136, layer-1 output)  -> 26112 B
    // RAW: async-staged fp32 feat, 32 channel-pair strips x 3 planes x 64:
    //     RAW[(c>>1)*192 + j*64 + (c&1)*32 + p]  -> 24576 B
    __shared__ unsigned short SM[96 * 136];
    __shared__ float RAW[32 * 192];
    #define X0V(r, c) SM[(r) * 72 + (c)]
    #define X1V(r, c) SM[(r) * 136 + (c)]

    const int t = threadIdx.x;
    const int b      = blockIdx.x >> 7;          // 8 batches x 128 groups
    const int base_n = (blockIdx.x & 127) << 7;  // 128 points (4 tiles x 32)

    const int w = t >> 6, lane = t & 63, lo = lane & 15, hi = lane >> 4;
    const int p32 = t & 31, cg = t >> 5;         // convert-phase coords
    const bool rel = t < 96;
    const int rp = t & 31, rk = t >> 5;          // relation coords (t<96)

    const uint4*  w1f = (const uint4*)ws;
    const uint4*  w2f = (const uint4*)(ws + 24576);
    const uint4*  w3f = (const uint4*)(ws + 40960);
    const float*  s1w = (const float*)(ws + 49152);
    const float*  t1w = (const float*)(ws + 49664);
    const float*  s2w = (const float*)(ws + 50176);
    const float*  t2w = (const float*)(ws + 50432);
    const float*  s3w = (const float*)(ws + 50688);
    const float*  t3w = (const float*)(ws + 50944);

    // Issue 48 async 4B global->LDS loads for this wave's 32 channels.
    // Inst (i,j): lane l reads feat[ch (cbase+2i+(l>>5))][pt n0s+(l&31)][float j]
    // -> LDS base+l*4 fills plane j of strip (w*16+i) linearly.
    auto stage_async = [&](int n0s) {
        #pragma unroll
        for (int i = 0; i < 16; ++i) {
            const int c = w * 32 + i * 2 + (lane >> 5);
            const float* gsrc = feat + ((size_t)(b * 64 + c) * N + n0s + (lane & 31)) * 16;
            float* lbase = &RAW[(size_t)(w * 16 + i) * 192];
            __builtin_amdgcn_global_load_lds(
                (const __attribute__((address_space(1))) void*)(gsrc + 0),
                (__attribute__((address_space(3))) void*)(lbase + 0), 4, 0, 0);
            __builtin_amdgcn_global_load_lds(
                (const __attribute__((address_space(1))) void*)(gsrc + 1),
                (__attribute__((address_space(3))) void*)(lbase + 64), 4, 0, 0);
            __builtin_amdgcn_global_load_lds(
                (const __attribute__((address_space(1))) void*)(gsrc + 2),
                (__attribute__((address_space(3))) void*)(lbase + 128), 4, 0, 0);
        }
    };

    float q0 = 0, q1 = 0, q2 = 0, q3 = 0, q4 = 0, q5 = 0;  // prefetched relation
    auto rel_load = [&](int n0s) {
        if (rel) {
            const int n = n0s + rp;
            q0 = src[((b * 3 + 0) * N + n) * 16 + rk]; q3 = tgt[(b * 3 + 0) * N + n];
            q1 = src[((b * 3 + 1) * N + n) * 16 + rk]; q4 = tgt[(b * 3 + 1) * N + n];
            q2 = src[((b * 3 + 2) * N + n) * 16 + rk]; q5 = tgt[(b * 3 + 2) * N + n];
        }
    };

    // prologue: stage tile 0
    stage_async(base_n);
    rel_load(base_n);

    #pragma unroll 1
    for (int tt = 0; tt < 4; ++tt) {
        const int n0 = base_n + tt * 32;

        // B0: RAW(tt) complete + X0 region free (prev tile's reads done)
        asm volatile("s_waitcnt vmcnt(0)" ::: "memory");
        __builtin_amdgcn_sched_barrier(0);
        __syncthreads();

        // ---- convert RAW -> X0 (bf16, verified R4 layout) ----
        #pragma unroll
        for (int j2 = 0; j2 < 4; ++j2) {
            const int c0 = cg * 16 + 4 * j2;
            float f[4][3];
            #pragma unroll
            for (int q = 0; q < 4; ++q) {
                const int c = c0 + q;
                const int base = (c >> 1) * 192 + (c & 1) * 32 + p32;
                f[q][0] = RAW[base];
                f[q][1] = RAW[base + 64];
                f[q][2] = RAW[base + 128];
            }
            uint2 u0, u1, u2;
            u0.x = f2bf(f[0][0]) | (f2bf(f[1][0]) << 16); u0.y = f2bf(f[2][0]) | (f2bf(f[3][0]) << 16);
            u1.x = f2bf(f[0][1]) | (f2bf(f[1][1]) << 16); u1.y = f2bf(f[2][1]) | (f2bf(f[3][1]) << 16);
            u2.x = f2bf(f[0][2]) | (f2bf(f[1][2]) << 16); u2.y = f2bf(f[2][2]) | (f2bf(f[3][2]) << 16);
            *(uint2*)&X0V(0 * 32 + p32, c0) = u0;
            *(uint2*)&X0V(1 * 32 + p32, c0) = u1;
            *(uint2*)&X0V(2 * 32 + p32, c0) = u2;
        }
        if (rel) {
            const float d0 = q0 - q3, d1 = q1 - q4, d2 = q2 - q5;
            const float ds = d0 * d0 + d1 * d1 + d2 * d2;
            uint2 wr; wr.x = f2bf(d0) | (f2bf(d1) << 16); wr.y = f2bf(d2) | (f2bf(ds) << 16);
            *(uint2*)&X0V(rk * 32 + rp, 64) = wr;
        }
        __syncthreads();   // B1: X0 staged

        // ---- layer 1 A-fragments: consume ALL of X0 into registers ----
        short8v a1[3][3];
        #pragma unroll
        for (int k = 0; k < 3; ++k) {
            const int row = k * 32 + w * 16 + lo;
            a1[k][0] = *(const short8v*)&X0V(row, hi * 8);
            a1[k][1] = *(const short8v*)&X0V(row, 32 + hi * 8);
            FragU U; U.u.x = 0; U.u.y = 0; U.u.z = 0; U.u.w = 0;
            if (hi == 0) U.h[0] = *(const uint2*)&X0V(row, 64);
            a1[k][2] = U.s;
        }
        __syncthreads();   // B2: X0 dead, X1 region free

        // ---- layer 1 : K=96 (68 real) -> 128, write X1 ----
        #pragma unroll 2
        for (int ct = 0; ct < 8; ++ct) {
            FragU B0, B1, B2;
            B0.u = w1f[(ct * 3 + 0) * 64 + lane];
            B1.u = w1f[(ct * 3 + 1) * 64 + lane];
            B2.u = w1f[(ct * 3 + 2) * 64 + lane];
            const float sc = s1w[ct * 16 + lo];
            const float tb = t1w[ct * 16 + lo];
            #pragma unroll
            for (int k = 0; k < 3; ++k) {
                f32x4 acc = {0.f, 0.f, 0.f, 0.f};
                acc = __builtin_amdgcn_mfma_f32_16x16x32_bf16(a1[k][0], B0.s, acc, 0, 0, 0);
                acc = __builtin_amdgcn_mfma_f32_16x16x32_bf16(a1[k][1], B1.s, acc, 0, 0, 0);
                acc = __builtin_amdgcn_mfma_f32_16x16x32_bf16(a1[k][2], B2.s, acc, 0, 0, 0);
                const int rb = k * 32 + w * 16 + 4 * hi;
                #pragma unroll
                for (int j = 0; j < 4; ++j) {
                    const float y = fmaxf(fmaf(sc, acc[j], tb), 0.f);
                    X1V(rb + j, ct * 16 + lo) = f2bf(y);
                }
            }
        }

        // ---- layer 2 A-fragments: consume X1 (wave-private rows) ----
        short8v a2[3][4];
        #pragma unroll
        for (int k = 0; k < 3; ++k) {
            const int row = k * 32 + w * 16 + lo;
            #pragma unroll
            for (int ks = 0; ks < 4; ++ks)
                a2[k][ks] = *(const short8v*)&X1V(row, ks * 32 + hi * 8);
        }
        __syncthreads();   // B3: X1 dead

        // ---- issue next tile's async stage + relation prefetch ----
        if (tt < 3) {
            stage_async(n0 + 32);
            rel_load(n0 + 32);
        }

        // ---- layer 2 : K=128 -> 64, write X2 (X0 view) ----
        #pragma unroll 2
        for (int ct = 0; ct < 4; ++ct) {
            FragU B0, B1, B2, B3;
            B0.u = w2f[(ct * 4 + 0) * 64 + lane];
            B1.u = w2f[(ct * 4 + 1) * 64 + lane];
            B2.u = w2f[(ct * 4 + 2) * 64 + lane];
            B3.u = w2f[(ct * 4 + 3) * 64 + lane];
            const float sc = s2w[ct * 16 + lo];
            const float tb = t2w[ct * 16 + lo];
            #pragma unroll
            for (int k = 0; k < 3; ++k) {
                f32x4 acc = {0.f, 0.f, 0.f, 0.f};
                acc = __builtin_amdgcn_mfma_f32_16x16x32_bf16(a2[k][0], B0.s, acc, 0, 0, 0);
                acc = __builtin_amdgcn_mfma_f32_16x16x32_bf16(a2[k][1], B1.s, acc, 0, 0, 0);
                acc = __builtin_amdgcn_mfma_f32_16x16x32_bf16(a2[k][2], B2.s, acc, 0, 0, 0);
                acc = __builtin_amdgcn_mfma_f32_16x16x32_bf16(a2[k][3], B3.s, acc, 0, 0, 0);
                const int rb = k * 32 + w * 16 + 4 * hi;
                #pragma unroll
                for (int j = 0; j < 4; ++j) {
                    const float y = fmaxf(fmaf(sc, acc[j], tb), 0.f);
                    X0V(rb + j, ct * 16 + lo) = f2bf(y);
                }
            }
        }

        // ---- layer 3 : K=64 -> 64, BN+ReLU per k then register k-sum ----
        short8v a3[3][2];
        #pragma unroll
        for (int k = 0; k < 3; ++k) {
            const int row = k * 32 + w * 16 + lo;
            a3[k][0] = *(const short8v*)&X0V(row, hi * 8);
            a3[k][1] = *(const short8v*)&X0V(row, 32 + hi * 8);
        }
        #pragma unroll 2
        for (int ct = 0; ct < 4; ++ct) {
            FragU B0, B1;
            B0.u = w3f[(ct * 2 + 0) * 64 + lane];
            B1.u = w3f[(ct * 2 + 1) * 64 + lane];
            const float sc = s3w[ct * 16 + lo];
            const float tb = t3w[ct * 16 + lo];
            f32x4 acc0 = {0.f, 0.f, 0.f, 0.f};
            f32x4 acc1 = {0.f, 0.f, 0.f, 0.f};
            f32x4 acc2 = {0.f, 0.f, 0.f, 0.f};
            acc0 = __builtin_amdgcn_mfma_f32_16x16x32_bf16(a3[0][0], B0.s, acc0, 0, 0, 0);
            acc0 = __builtin_amdgcn_mfma_f32_16x16x32_bf16(a3[0][1], B1.s, acc0, 0, 0, 0);
            acc1 = __builtin_amdgcn_mfma_f32_16x16x32_bf16(a3[1][0], B0.s, acc1, 0, 0, 0);
            acc1 = __builtin_amdgcn_mfma_f32_16x16x32_bf16(a3[1][1], B1.s, acc1, 0, 0, 0);
            acc2 = __builtin_amdgcn_mfma_f32_16x16x32_bf16(a3[2][0], B0.s, acc2, 0, 0, 0);
            acc2 = __builtin_amdgcn_mfma_f32_16x16x32_bf16(a3[2][1], B1.s, acc2, 0, 0, 0);
            float4 r;
            float* rp4 = &r.x;
            #pragma unroll
            for (int j = 0; j < 4; ++j) {
                rp4[j] = fmaxf(fmaf(sc, acc0[j], tb), 0.f)
                       + fmaxf(fmaf(sc, acc1[j], tb), 0.f)
                       + fmaxf(fmaf(sc, acc2[j], tb), 0.f);
            }
            float* op = out + (size_t)(b * 64 + ct * 16 + lo) * N + n0 + w * 16 + 4 * hi;
            *(float4*)op = r;   // 4 lanes per o cover a full 64B line
        }
    }
    #undef X0V
    #undef X1V
}

extern "C" void kernel_launch(void* const* d_in, const int* in_sizes, int n_in,
                              void* d_out, int out_size, void* d_ws, size_t ws_size,
                              hipStream_t stream)
{
    const float* src  = (const float*)d_in[0];
    const float* tgt  = (const float*)d_in[1];
    const float* feat = (const float*)d_in[2];
    const float* W1 = (const float*)d_in[3];
    const float* g1 = (const float*)d_in[4];
    const float* b1 = (const float*)d_in[5];
    const float* m1 = (const float*)d_in[6];
    const float* v1 = (const float*)d_in[7];
    const float* W2 = (const float*)d_in[8];
    const float* g2 = (const float*)d_in[9];
    const float* b2 = (const float*)d_in[10];
    const float* m2 = (const float*)d_in[11];
    const float* v2 = (const float*)d_in[12];
    const float* W3 = (const float*)d_in[13];
    const float* g3 = (const float*)d_in[14];
    const float* b3 = (const float*)d_in[15];
    const float* m3 = (const float*)d_in[16];
    const float* v3 = (const float*)d_in[17];
    float* out = (float*)d_out;
    char* ws = (char*)d_ws;

    hipLaunchKernelGGL(fa_pack, dim3(13), dim3(256), 0, stream,
                       W1, g1, b1, m1, v1, W2, g2, b2, m2, v2, W3, g3, b3, m3, v3, ws);
    hipLaunchKernelGGL(fa_mfma, dim3(1024), dim3(128), 0, stream,
                       src, tgt, feat, ws, out);
}

// Round 11
// 153.286 us; speedup vs baseline: 1.5071x; 1.3022x over previous
//
#include <hip/hip_runtime.h>

// FeatureAggregation via MFMA bf16 (fp32 accumulate).
// R7 verified 64-pt compute core + depth-1 register prefetch with DRAIN-FREE
// barriers: next tile's 16 feat loads are issued right after this tile's
// convert frees the registers, and all block barriers are raw
// lgkmcnt(0)+s_barrier (no vmcnt drain - the __syncthreads drain was why
// every previous pipeline attempt failed). Loads stay in flight across the
// whole compute phase; HBM idles only during the short convert.
// B=8, C=64, N=16384, K=16, only k<3 used (reference quirk).

typedef __attribute__((ext_vector_type(8))) short short8v;
typedef __attribute__((ext_vector_type(4))) float f32x4;

#define BN_EPS 1e-5f

// lgkm-only barrier: orders LDS (ds) ops across waves WITHOUT draining vmem.
// All inter-wave hazards in this kernel are LDS write->read or read->reuse;
// in-flight global loads are wave-private VGPR dests (compiler inserts its
// own vmcnt waits before their first use).
#define BAR_LGKM() do {                                          \
    __builtin_amdgcn_sched_barrier(0);                           \
    asm volatile("s_waitcnt lgkmcnt(0)" ::: "memory");           \
    __builtin_amdgcn_s_barrier();                                \
    __builtin_amdgcn_sched_barrier(0);                           \
} while (0)

__device__ __forceinline__ unsigned short f2bf(float f) {
    union { float f; unsigned u; } U; U.f = f;
    unsigned r = U.u + 0x7FFFu + ((U.u >> 16) & 1u);   // RNE; inputs finite
    return (unsigned short)(r >> 16);
}

union FragU { uint4 u; short8v s; uint2 h[2]; };

// ---- d_ws layout (bytes) ----
//     0 : W1 frags uint4[1536]  (frag = ct*3+ks; zero-pad k>=68)
// 24576 : W2 frags uint4[1024]  (frag = ct*4+ks)
// 40960 : W3 frags uint4[512]   (frag = ct*2+ks)
// 49152 : s1[128]  49664 : t1[128]
// 50176 : s2[64]   50432 : t2[64]
// 50688 : s3[64]   50944 : t3[64]

__global__ __launch_bounds__(256) void fa_pack(
    const float* __restrict__ W1, const float* __restrict__ g1, const float* __restrict__ b1,
    const float* __restrict__ m1, const float* __restrict__ v1,
    const float* __restrict__ W2, const float* __restrict__ g2, const float* __restrict__ b2,
    const float* __restrict__ m2, const float* __restrict__ v2,
    const float* __restrict__ W3, const float* __restrict__ g3, const float* __restrict__ b3,
    const float* __restrict__ m3, const float* __restrict__ v3,
    char* __restrict__ ws)
{
    const int id = blockIdx.x * 256 + threadIdx.x;
    if (id < 1536) {                       // W1: 96(K,zero-padded) x 128
        const int lane = id & 63, frag = id >> 6;
        const int ct = frag / 3, ks = frag - 3 * ct;
        const int o  = ct * 16 + (lane & 15);
        const int kb = ks * 32 + (lane >> 4) * 8;
        unsigned short h[8];
        #pragma unroll
        for (int j = 0; j < 8; ++j) {
            const int k = kb + j;
            h[j] = (k < 68) ? f2bf(W1[o * 68 + k]) : (unsigned short)0;
        }
        uint4 pk;
        pk.x = h[0] | (h[1] << 16); pk.y = h[2] | (h[3] << 16);
        pk.z = h[4] | (h[5] << 16); pk.w = h[6] | (h[7] << 16);
        ((uint4*)ws)[id] = pk;
    } else if (id < 2560) {                // W2: 128 x 64
        const int i2 = id - 1536;
        const int lane = i2 & 63, frag = i2 >> 6;
        const int o  = (frag >> 2) * 16 + (lane & 15);
        const int kb = (frag & 3) * 32 + (lane >> 4) * 8;
        unsigned short h[8];
        #pragma unroll
        for (int j = 0; j < 8; ++j) h[j] = f2bf(W2[o * 128 + kb + j]);
        uint4 pk;
        pk.x = h[0] | (h[1] << 16); pk.y = h[2] | (h[3] << 16);
        pk.z = h[4] | (h[5] << 16); pk.w = h[6] | (h[7] << 16);
        ((uint4*)(ws + 24576))[i2] = pk;
    } else if (id < 3072) {                // W3: 64 x 64
        const int i3 = id - 2560;
        const int lane = i3 & 63, frag = i3 >> 6;
        const int o  = (frag >> 1) * 16 + (lane & 15);
        const int kb = (frag & 1) * 32 + (lane >> 4) * 8;
        unsigned short h[8];
        #pragma unroll
        for (int j = 0; j < 8; ++j) h[j] = f2bf(W3[o * 64 + kb + j]);
        uint4 pk;
        pk.x = h[0] | (h[1] << 16); pk.y = h[2] | (h[3] << 16);
        pk.z = h[4] | (h[5] << 16); pk.w = h[6] | (h[7] << 16);
        ((uint4*)(ws + 40960))[i3] = pk;
    } else if (id < 3200) {                // BN fold L1
        const int o = id - 3072;
        const float s = g1[o] * rsqrtf(v1[o] + BN_EPS);
        ((float*)(ws + 49152))[o] = s;
        ((float*)(ws + 49664))[o] = b1[o] - m1[o] * s;
    } else if (id < 3264) {                // BN fold L2
        const int o = id - 3200;
        const float s = g2[o] * rsqrtf(v2[o] + BN_EPS);
        ((float*)(ws + 50176))[o] = s;
        ((float*)(ws + 50432))[o] = b2[o] - m2[o] * s;
    } else if (id < 3328) {                // BN fold L3
        const int o = id - 3264;
        const float s = g3[o] * rsqrtf(v3[o] + BN_EPS);
        ((float*)(ws + 50688))[o] = s;
        ((float*)(ws + 50944))[o] = b3[o] - m3[o] * s;
    }
}

__global__ __launch_bounds__(256, 2) void fa_mfma(
    const float* __restrict__ src, const float* __restrict__ tgt,
    const float* __restrict__ feat,
    const char* __restrict__ ws, float* __restrict__ out)
{
    constexpr int N = 16384;
    // ONE shared buffer, overlaid views (phases separated by lgkm barriers):
    //   X0 view: 192 rows (k*64+p) x stride 72 (input; later layer-2 output X2)
    //   X1 view: 192 rows x stride 136 (layer-1 output)
    __shared__ unsigned short SM[192 * 136];   // 52224 B
    #define X0V(r, c) SM[(r) * 72 + (c)]
    #define X1V(r, c) SM[(r) * 136 + (c)]

    const int t = threadIdx.x;
    const int b      = blockIdx.x >> 6;          // 512 blocks: 8 b x 64 groups
    const int base_n = (blockIdx.x & 63) << 8;   // 256 points (4 tiles x 64)

    const int p  = t & 63;
    const int cg = t >> 6;                       // 0..3 (16 channels each)
    const bool rel = t < 192;
    const int rp = t & 63, rk = t >> 6;          // relation coords (t<192)
    const int w = t >> 6, lane = t & 63, lo = lane & 15, hi = lane >> 4;

    const uint4*  w1f = (const uint4*)ws;
    const uint4*  w2f = (const uint4*)(ws + 24576);
    const uint4*  w3f = (const uint4*)(ws + 40960);
    const float*  s1w = (const float*)(ws + 49152);
    const float*  t1w = (const float*)(ws + 49664);
    const float*  s2w = (const float*)(ws + 50176);
    const float*  t2w = (const float*)(ws + 50432);
    const float*  s3w = (const float*)(ws + 50688);
    const float*  t3w = (const float*)(ws + 50944);

    float4 fr[16];
    float q0 = 0, q1 = 0, q2 = 0, q3 = 0, q4 = 0, q5 = 0;

    // issue the 16 contiguous-wave feat loads + relation loads for tile n0s
    auto issue_loads = [&](int n0s) {
        #pragma unroll
        for (int i = 0; i < 16; ++i) {
            const int c = cg * 16 + i;
            fr[i] = *(const float4*)(feat + ((size_t)(b * 64 + c) * N + n0s + p) * 16);
        }
        if (rel) {
            const int n = n0s + rp;
            q0 = src[((b * 3 + 0) * N + n) * 16 + rk]; q3 = tgt[(b * 3 + 0) * N + n];
            q1 = src[((b * 3 + 1) * N + n) * 16 + rk]; q4 = tgt[(b * 3 + 1) * N + n];
            q2 = src[((b * 3 + 2) * N + n) * 16 + rk]; q5 = tgt[(b * 3 + 2) * N + n];
        }
    };

    issue_loads(base_n);   // prologue: tile 0 in flight

    #pragma unroll 1
    for (int tt = 0; tt < 4; ++tt) {
        const int n0 = base_n + tt * 64;

        // TOP barrier: previous tile's a3/X2 LDS reads done -> X0 free.
        BAR_LGKM();

        // ---- convert held regs -> X0 (compiler inserts vmcnt waits) ----
        {
            #pragma unroll
            for (int j = 0; j < 4; ++j) {
                const int c0 = cg * 16 + 4 * j;
                const float4 f0 = fr[4 * j + 0], f1 = fr[4 * j + 1];
                const float4 f2 = fr[4 * j + 2], f3 = fr[4 * j + 3];
                uint2 u0, u1, u2;
                u0.x = f2bf(f0.x) | (f2bf(f1.x) << 16); u0.y = f2bf(f2.x) | (f2bf(f3.x) << 16);
                u1.x = f2bf(f0.y) | (f2bf(f1.y) << 16); u1.y = f2bf(f2.y) | (f2bf(f3.y) << 16);
                u2.x = f2bf(f0.z) | (f2bf(f1.z) << 16); u2.y = f2bf(f2.z) | (f2bf(f3.z) << 16);
                *(uint2*)&X0V(0 * 64 + p, c0) = u0;
                *(uint2*)&X0V(1 * 64 + p, c0) = u1;
                *(uint2*)&X0V(2 * 64 + p, c0) = u2;
            }
            if (rel) {
                const float d0 = q0 - q3, d1 = q1 - q4, d2 = q2 - q5;
                const float ds = d0 * d0 + d1 * d1 + d2 * d2;
                uint2 wr; wr.x = f2bf(d0) | (f2bf(d1) << 16); wr.y = f2bf(d2) | (f2bf(ds) << 16);
                *(uint2*)&X0V(rk * 64 + rp, 64) = wr;
            }
        }

        // ---- issue NEXT tile's loads: in flight across the whole compute ----
        if (tt < 3) issue_loads(n0 + 64);

        BAR_LGKM();   // B1: X0 staged

        // ---- layer 1 A-fragments: consume ALL of X0 into registers ----
        short8v a1[3][3];
        #pragma unroll
        for (int k = 0; k < 3; ++k) {
            const int row = k * 64 + w * 16 + lo;
            a1[k][0] = *(const short8v*)&X0V(row, hi * 8);
            a1[k][1] = *(const short8v*)&X0V(row, 32 + hi * 8);
            FragU U; U.u.x = 0; U.u.y = 0; U.u.z = 0; U.u.w = 0;
            if (hi == 0) U.h[0] = *(const uint2*)&X0V(row, 64);
            a1[k][2] = U.s;
        }
        BAR_LGKM();   // B2: X0 dead, X1 region free

        // ---- layer 1 : K=96 (68 real) -> 128, write X1 ----
        #pragma unroll 2
        for (int ct = 0; ct < 8; ++ct) {
            FragU B0, B1, B2;
            B0.u = w1f[(ct * 3 + 0) * 64 + lane];
            B1.u = w1f[(ct * 3 + 1) * 64 + lane];
            B2.u = w1f[(ct * 3 + 2) * 64 + lane];
            const float sc = s1w[ct * 16 + lo];
            const float tb = t1w[ct * 16 + lo];
            #pragma unroll
            for (int k = 0; k < 3; ++k) {
                f32x4 acc = {0.f, 0.f, 0.f, 0.f};
                acc = __builtin_amdgcn_mfma_f32_16x16x32_bf16(a1[k][0], B0.s, acc, 0, 0, 0);
                acc = __builtin_amdgcn_mfma_f32_16x16x32_bf16(a1[k][1], B1.s, acc, 0, 0, 0);
                acc = __builtin_amdgcn_mfma_f32_16x16x32_bf16(a1[k][2], B2.s, acc, 0, 0, 0);
                const int rb = k * 64 + w * 16 + 4 * hi;
                #pragma unroll
                for (int j = 0; j < 4; ++j) {
                    const float y = fmaxf(fmaf(sc, acc[j], tb), 0.f);
                    X1V(rb + j, ct * 16 + lo) = f2bf(y);
                }
            }
        }

        // ---- layer 2 A-fragments: consume X1 (wave-private rows) ----
        short8v a2[3][4];
        #pragma unroll
        for (int k = 0; k < 3; ++k) {
            const int row = k * 64 + w * 16 + lo;
            #pragma unroll
            for (int ks = 0; ks < 4; ++ks)
                a2[k][ks] = *(const short8v*)&X1V(row, ks * 32 + hi * 8);
        }
        BAR_LGKM();   // B3: X1 dead

        // ---- layer 2 : K=128 -> 64, write X2 (X0 view) ----
        #pragma unroll 2
        for (int ct = 0; ct < 4; ++ct) {
            FragU B0, B1, B2, B3;
            B0.u = w2f[(ct * 4 + 0) * 64 + lane];
            B1.u = w2f[(ct * 4 + 1) * 64 + lane];
            B2.u = w2f[(ct * 4 + 2) * 64 + lane];
            B3.u = w2f[(ct * 4 + 3) * 64 + lane];
            const float sc = s2w[ct * 16 + lo];
            const float tb = t2w[ct * 16 + lo];
            #pragma unroll
            for (int k = 0; k < 3; ++k) {
                f32x4 acc = {0.f, 0.f, 0.f, 0.f};
                acc = __builtin_amdgcn_mfma_f32_16x16x32_bf16(a2[k][0], B0.s, acc, 0, 0, 0);
                acc = __builtin_amdgcn_mfma_f32_16x16x32_bf16(a2[k][1], B1.s, acc, 0, 0, 0);
                acc = __builtin_amdgcn_mfma_f32_16x16x32_bf16(a2[k][2], B2.s, acc, 0, 0, 0);
                acc = __builtin_amdgcn_mfma_f32_16x16x32_bf16(a2[k][3], B3.s, acc, 0, 0, 0);
                const int rb = k * 64 + w * 16 + 4 * hi;
                #pragma unroll
                for (int j = 0; j < 4; ++j) {
                    const float y = fmaxf(fmaf(sc, acc[j], tb), 0.f);
                    X0V(rb + j, ct * 16 + lo) = f2bf(y);
                }
            }
        }

        // ---- layer 3 : K=64 -> 64 (wave-private X2 rows), k-sum, store ----
        short8v a3[3][2];
        #pragma unroll
        for (int k = 0; k < 3; ++k) {
            const int row = k * 64 + w * 16 + lo;
            a3[k][0] = *(const short8v*)&X0V(row, hi * 8);
            a3[k][1] = *(const short8v*)&X0V(row, 32 + hi * 8);
        }
        #pragma unroll 2
        for (int ct = 0; ct < 4; ++ct) {
            FragU B0, B1;
            B0.u = w3f[(ct * 2 + 0) * 64 + lane];
            B1.u = w3f[(ct * 2 + 1) * 64 + lane];
            const float sc = s3w[ct * 16 + lo];
            const float tb = t3w[ct * 16 + lo];
            f32x4 acc0 = {0.f, 0.f, 0.f, 0.f};
            f32x4 acc1 = {0.f, 0.f, 0.f, 0.f};
            f32x4 acc2 = {0.f, 0.f, 0.f, 0.f};
            acc0 = __builtin_amdgcn_mfma_f32_16x16x32_bf16(a3[0][0], B0.s, acc0, 0, 0, 0);
            acc0 = __builtin_amdgcn_mfma_f32_16x16x32_bf16(a3[0][1], B1.s, acc0, 0, 0, 0);
            acc1 = __builtin_amdgcn_mfma_f32_16x16x32_bf16(a3[1][0], B0.s, acc1, 0, 0, 0);
            acc1 = __builtin_amdgcn_mfma_f32_16x16x32_bf16(a3[1][1], B1.s, acc1, 0, 0, 0);
            acc2 = __builtin_amdgcn_mfma_f32_16x16x32_bf16(a3[2][0], B0.s, acc2, 0, 0, 0);
            acc2 = __builtin_amdgcn_mfma_f32_16x16x32_bf16(a3[2][1], B1.s, acc2, 0, 0, 0);
            float4 r;
            float* rp4 = &r.x;
            #pragma unroll
            for (int j = 0; j < 4; ++j) {
                rp4[j] = fmaxf(fmaf(sc, acc0[j], tb), 0.f)
                       + fmaxf(fmaf(sc, acc1[j], tb), 0.f)
                       + fmaxf(fmaf(sc, acc2[j], tb), 0.f);
            }
            float* op = out + (size_t)(b * 64 + ct * 16 + lo) * N + n0 + w * 16 + 4 * hi;
            *(float4*)op = r;   // 4 lanes per o cover a full 64B line
        }
    }
    #undef X0V
    #undef X1V
}

extern "C" void kernel_launch(void* const* d_in, const int* in_sizes, int n_in,
                              void* d_out, int out_size, void* d_ws, size_t ws_size,
                              hipStream_t stream)
{
    const float* src  = (const float*)d_in[0];
    const float* tgt  = (const float*)d_in[1];
    const float* feat = (const float*)d_in[2];
    const float* W1 = (const float*)d_in[3];
    const float* g1 = (const float*)d_in[4];
    const float* b1 = (const float*)d_in[5];
    const float* m1 = (const float*)d_in[6];
    const float* v1 = (const float*)d_in[7];
    const float* W2 = (const float*)d_in[8];
    const float* g2 = (const float*)d_in[9];
    const float* b2 = (const float*)d_in[10];
    const float* m2 = (const float*)d_in[11];
    const float* v2 = (const float*)d_in[12];
    const float* W3 = (const float*)d_in[13];
    const float* g3 = (const float*)d_in[14];
    const float* b3 = (const float*)d_in[15];
    const float* m3 = (const float*)d_in[16];
    const float* v3 = (const float*)d_in[17];
    float* out = (float*)d_out;
    char* ws = (char*)d_ws;

    hipLaunchKernelGGL(fa_pack, dim3(13), dim3(256), 0, stream,
                       W1, g1, b1, m1, v1, W2, g2, b2, m2, v2, W3, g3, b3, m3, v3, ws);
    hipLaunchKernelGGL(fa_mfma, dim3(512), dim3(256), 0, stream,
                       src, tgt, feat, ws, out);
}